// Round 4
// baseline (965.238 us; speedup 1.0000x reference)
//
#include <hip/hip_runtime.h>

#define B_  128
#define LC_ 512
#define LM_ 512
#define D_  512

// ---------------- K0: u[b,c] = ctx[b,c,:]W ; v[b,m] = main[b,m,:]W ----------
__global__ __launch_bounds__(256) void k_uv(const float* __restrict__ ctx,
                                            const float* __restrict__ mn,
                                            const float* __restrict__ W,
                                            float* __restrict__ u,
                                            float* __restrict__ v) {
  int wave = blockIdx.x * 4 + (threadIdx.x >> 6);
  int lane = threadIdx.x & 63;
  int b = wave >> 10;          // 1024 rows per batch (512 ctx + 512 main)
  int r = wave & 1023;
  const float* src;
  float* dst;
  if (r < LC_) { src = ctx + ((size_t)b * LC_ + r) * D_; dst = u + b * LC_ + r; }
  else { r -= LC_; src = mn + ((size_t)b * LM_ + r) * D_; dst = v + b * LM_ + r; }
  const float4* s4 = (const float4*)src + lane * 2;
  const float4* w4 = (const float4*)W   + lane * 2;
  float4 a0 = s4[0], a1 = s4[1];
  float4 b0 = w4[0], b1 = w4[1];
  float acc = a0.x*b0.x + a0.y*b0.y + a0.z*b0.z + a0.w*b0.w
            + a1.x*b1.x + a1.y*b1.y + a1.z*b1.z + a1.w*b1.w;
  #pragma unroll
  for (int s = 32; s >= 1; s >>= 1) acc += __shfl_xor(acc, s, 64);
  if (lane == 0) *dst = acc;
}

// ---------------- K1: P[b,c,m] = softmax_m( ctx[b,c,:]·main[b,m,:] ) -------
// Block: 32 c-rows x full 512 m. 256 threads: tm (32) x tc (8).
// Thread owns rows tc*4+i (i<4), cols tm+32j (j<16). acc[4][16].
#define CT  32
#define KK  16
#define SMP 20   // padded LDS row stride (floats): conflict-free b128 reads

__global__ __launch_bounds__(256) void k_scores_softmax(
    const float* __restrict__ ctx, const float* __restrict__ mn,
    float* __restrict__ P) {
  int b  = blockIdx.y;
  int c0 = blockIdx.x * CT;
  const float* Cg = ctx + ((size_t)b * LC_ + c0) * D_;
  const float* Mg = mn + (size_t)b * LM_ * D_;
  __shared__ float sC[CT * SMP];
  __shared__ float sM[LM_ * SMP];
  int tid = threadIdx.x;
  int tm = tid & 31;
  int tc = tid >> 5;
  float acc[4][16];
  #pragma unroll
  for (int i = 0; i < 4; i++)
    #pragma unroll
    for (int j = 0; j < 16; j++) acc[i][j] = 0.f;

  for (int k0 = 0; k0 < D_; k0 += KK) {
    if (tid < 128) {                       // stage A: 32x16 floats
      int idx = tid * 4;
      int r = idx >> 4, kk = idx & 15;
      *(float4*)&sC[r * SMP + kk] = *(const float4*)&Cg[(size_t)r * D_ + k0 + kk];
    }
    #pragma unroll
    for (int j = 0; j < 8; j++) {          // stage B: 512x16 floats
      int idx = (tid + j * 256) * 4;
      int m = idx >> 4, kk = idx & 15;
      *(float4*)&sM[m * SMP + kk] = *(const float4*)&Mg[(size_t)m * D_ + k0 + kk];
    }
    __syncthreads();
    #pragma unroll
    for (int kq = 0; kq < KK; kq += 4) {
      float4 a[4];
      #pragma unroll
      for (int i = 0; i < 4; i++)
        a[i] = *(const float4*)&sC[(tc * 4 + i) * SMP + kq];
      #pragma unroll
      for (int j = 0; j < 16; j++) {
        float4 bb = *(const float4*)&sM[(tm + 32 * j) * SMP + kq];
        #pragma unroll
        for (int i = 0; i < 4; i++) {
          acc[i][j] = fmaf(a[i].x, bb.x, acc[i][j]);
          acc[i][j] = fmaf(a[i].y, bb.y, acc[i][j]);
          acc[i][j] = fmaf(a[i].z, bb.z, acc[i][j]);
          acc[i][j] = fmaf(a[i].w, bb.w, acc[i][j]);
        }
      }
    }
    __syncthreads();
  }

  // row softmax over m: reduce across the 32 tm-lanes (same tc)
  float* Pb = P + ((size_t)b * LC_ + c0) * LM_;
  #pragma unroll
  for (int i = 0; i < 4; i++) {
    float mx = acc[i][0];
    #pragma unroll
    for (int j = 1; j < 16; j++) mx = fmaxf(mx, acc[i][j]);
    #pragma unroll
    for (int s = 16; s >= 1; s >>= 1) mx = fmaxf(mx, __shfl_xor(mx, s, 64));
    float p[16];
    float sum = 0.f;
    #pragma unroll
    for (int j = 0; j < 16; j++) { p[j] = __expf(acc[i][j] - mx); sum += p[j]; }
    #pragma unroll
    for (int s = 16; s >= 1; s >>= 1) sum += __shfl_xor(sum, s, 64);
    float rinv = 1.0f / sum;
    float* Pr = Pb + (size_t)(tc * 4 + i) * LM_;
    #pragma unroll
    for (int j = 0; j < 16; j++) Pr[tm + 32 * j] = p[j] * rinv;
  }
}

// ---------------- K2: t[b,m] = v[b,m] - sum_c P[b,c,m]*u[b,c] --------------
__global__ __launch_bounds__(256) void k_t(const float* __restrict__ P,
                                           const float* __restrict__ u,
                                           const float* __restrict__ v,
                                           float* __restrict__ t) {
  int b = blockIdx.y;
  int m0 = blockIdx.x * 64;
  int tm = threadIdx.x & 63;
  int tg = threadIdx.x >> 6;
  const float* Pb = P + (size_t)b * LC_ * LM_ + m0;
  const float* ub = u + b * LC_;
  float acc = 0.f;
  #pragma unroll 4
  for (int c = tg; c < LC_; c += 4)
    acc += Pb[(size_t)c * LM_ + tm] * ub[c];
  __shared__ float red[4][64];
  red[tg][tm] = acc;
  __syncthreads();
  if (tg == 0) {
    float s = red[0][tm] + red[1][tm] + red[2][tm] + red[3][tm];
    t[b * LM_ + m0 + tm] = v[b * LM_ + m0 + tm] - s;
  }
}

// ---------------- K3: w[b,:] = softmax_m(t[b,:]) ---------------------------
__global__ __launch_bounds__(256) void k_w(const float* __restrict__ t,
                                           float* __restrict__ w) {
  int b = blockIdx.x;
  int tid = threadIdx.x;
  const float* tb = t + b * LM_;
  float2 x = *(const float2*)&tb[tid * 2];
  float mx = fmaxf(x.x, x.y);
  #pragma unroll
  for (int s = 32; s >= 1; s >>= 1) mx = fmaxf(mx, __shfl_xor(mx, s, 64));
  __shared__ float redm[4], reds[4];
  int wv = tid >> 6, ln = tid & 63;
  if (ln == 0) redm[wv] = mx;
  __syncthreads();
  mx = fmaxf(fmaxf(redm[0], redm[1]), fmaxf(redm[2], redm[3]));
  float e0 = __expf(x.x - mx), e1 = __expf(x.y - mx);
  float sum = e0 + e1;
  #pragma unroll
  for (int s = 32; s >= 1; s >>= 1) sum += __shfl_xor(sum, s, 64);
  if (ln == 0) reds[wv] = sum;
  __syncthreads();
  sum = reds[0] + reds[1] + reds[2] + reds[3];
  float rinv = 1.0f / sum;
  float2 o; o.x = e0 * rinv; o.y = e1 * rinv;
  *(float2*)&w[b * LM_ + tid * 2] = o;
}

// ---------------- K4: q[b,c] = sum_m P[b,c,m]*w[b,m] -----------------------
__global__ __launch_bounds__(256) void k_q(const float* __restrict__ P,
                                           const float* __restrict__ w,
                                           float* __restrict__ q) {
  int b = blockIdx.y;
  int c0 = blockIdx.x * 32;
  int wv = threadIdx.x >> 6, ln = threadIdx.x & 63;
  __shared__ float sw[LM_];
  *(float2*)&sw[threadIdx.x * 2] = *(const float2*)&w[b * LM_ + threadIdx.x * 2];
  __syncthreads();
  #pragma unroll
  for (int rr = 0; rr < 8; rr++) {
    int c = c0 + wv * 8 + rr;
    const float4* Pr = (const float4*)(P + ((size_t)b * LC_ + c) * LM_) + ln * 2;
    float4 p0 = Pr[0], p1 = Pr[1];
    const float4* wr = (const float4*)sw + ln * 2;
    float4 w0 = wr[0], w1 = wr[1];
    float acc = p0.x*w0.x + p0.y*w0.y + p0.z*w0.z + p0.w*w0.w
              + p1.x*w1.x + p1.y*w1.y + p1.z*w1.z + p1.w*w1.w;
    #pragma unroll
    for (int s = 32; s >= 1; s >>= 1) acc += __shfl_xor(acc, s, 64);
    if (ln == 0) q[b * LC_ + c] = acc;
  }
}

// ---------------- K5: out[b,d] = sum_m w*main - sum_c q*ctx ----------------
__global__ __launch_bounds__(256) void k_out(const float* __restrict__ ctx,
                                             const float* __restrict__ mn,
                                             const float* __restrict__ w,
                                             const float* __restrict__ q,
                                             float* __restrict__ out) {
  int b = blockIdx.y;
  int d0 = blockIdx.x * 64;
  int td = threadIdx.x & 63;
  int tg = threadIdx.x >> 6;
  const float* Mb = mn  + (size_t)b * LM_ * D_ + d0;
  const float* Cb = ctx + (size_t)b * LC_ * D_ + d0;
  const float* wb = w + b * LM_;
  const float* qb = q + b * LC_;
  float acc = 0.f;
  #pragma unroll 4
  for (int m = tg; m < LM_; m += 4) acc += wb[m] * Mb[(size_t)m * D_ + td];
  #pragma unroll 4
  for (int c = tg; c < LC_; c += 4) acc -= qb[c] * Cb[(size_t)c * D_ + td];
  __shared__ float red[4][64];
  red[tg][td] = acc;
  __syncthreads();
  if (tg == 0)
    out[b * D_ + d0 + td] = red[0][td] + red[1][td] + red[2][td] + red[3][td];
}

extern "C" void kernel_launch(void* const* d_in, const int* in_sizes, int n_in,
                              void* d_out, int out_size, void* d_ws, size_t ws_size,
                              hipStream_t stream) {
  const float* ctx = (const float*)d_in[0];
  const float* mn  = (const float*)d_in[1];
  const float* W   = (const float*)d_in[2];
  float* out = (float*)d_out;

  float* ws = (float*)d_ws;
  size_t nP = (size_t)B_ * LC_ * LM_;          // 33.55M floats = 134.2 MB
  float* P = ws;
  float* u = ws + nP;                          // B*LC
  float* v = u + (size_t)B_ * LC_;             // B*LM
  float* t = v + (size_t)B_ * LM_;             // B*LM
  float* w = t + (size_t)B_ * LM_;             // B*LM
  float* q = w + (size_t)B_ * LM_;             // B*LC

  k_uv<<<dim3(B_ * 1024 / 4), 256, 0, stream>>>(ctx, mn, W, u, v);
  k_scores_softmax<<<dim3(LC_ / CT, B_), 256, 0, stream>>>(ctx, mn, P);
  k_t<<<dim3(LM_ / 64, B_), 256, 0, stream>>>(P, u, v, t);
  k_w<<<dim3(B_), 256, 0, stream>>>(t, w);
  k_q<<<dim3(LC_ / 32, B_), 256, 0, stream>>>(P, w, q);
  k_out<<<dim3(D_ / 64, B_), 256, 0, stream>>>(ctx, mn, w, q, out);
}

// Round 5
// 408.847 us; speedup vs baseline: 2.3609x; 2.3609x over previous
//
#include <hip/hip_runtime.h>

#define B_  128
#define LC_ 512
#define LM_ 512
#define D_  512

typedef __attribute__((ext_vector_type(8))) short short8;
typedef __attribute__((ext_vector_type(16))) float f32x16;

__device__ __forceinline__ unsigned short bf16_rn(float x) {
  unsigned u = __float_as_uint(x);
  unsigned r = u + 0x7fffu + ((u >> 16) & 1u);
  return (unsigned short)(r >> 16);
}

// ---------------- K0: u[b,c] = ctx[b,c,:]W ; v[b,m] = main[b,m,:]W ----------
__global__ __launch_bounds__(256) void k_uv(const float* __restrict__ ctx,
                                            const float* __restrict__ mn,
                                            const float* __restrict__ W,
                                            float* __restrict__ u,
                                            float* __restrict__ v) {
  int wave = blockIdx.x * 4 + (threadIdx.x >> 6);
  int lane = threadIdx.x & 63;
  int b = wave >> 10;
  int r = wave & 1023;
  const float* src;
  float* dst;
  if (r < LC_) { src = ctx + ((size_t)b * LC_ + r) * D_; dst = u + b * LC_ + r; }
  else { r -= LC_; src = mn + ((size_t)b * LM_ + r) * D_; dst = v + b * LM_ + r; }
  const float4* s4 = (const float4*)src + lane * 2;
  const float4* w4 = (const float4*)W   + lane * 2;
  float4 a0 = s4[0], a1 = s4[1];
  float4 b0 = w4[0], b1 = w4[1];
  float acc = a0.x*b0.x + a0.y*b0.y + a0.z*b0.z + a0.w*b0.w
            + a1.x*b1.x + a1.y*b1.y + a1.z*b1.z + a1.w*b1.w;
  #pragma unroll
  for (int s = 32; s >= 1; s >>= 1) acc += __shfl_xor(acc, s, 64);
  if (lane == 0) *dst = acc;
}

// ---------------- K1: fused scores+softmax via split-bf16 MFMA -------------
// Block: 64 c-rows x 512 m, 256 threads = 4 waves; wave w owns all 64 c and
// m in [128w, 128w+128). MFMA 32x32x16 bf16, 3-term split (hh + hl + lh).
// LDS: fragment-ordered bf16 hi/lo chunks (lane-linear 16B) => conflict-free
// ds_read_b128/ds_write_b128. Double-buffered, 1 barrier per K-step.
struct __align__(16) Smem1 {
  short Bf[2][2][16 * 64 * 8];  // [buf][hi/lo][(mt*64+l)*8]  64 KB
  short Af[2][2][2 * 64 * 8];   // [buf][hi/lo][(rt*64+l)*8]   8 KB
  float red[4][64];
  float cmb[64];
};

__global__ __launch_bounds__(256, 2) void k_scores_mfma(
    const float* __restrict__ ctx, const float* __restrict__ mn,
    float* __restrict__ P) {
  __shared__ Smem1 sm;
  int b   = blockIdx.y;
  int c0  = blockIdx.x * 64;
  int tid = threadIdx.x;
  int lane = tid & 63;
  int w = tid >> 6;
  int h = lane >> 5;
  const float* Cg = ctx + ((size_t)b * LC_ + c0) * D_;
  const float* Mg = mn + (size_t)b * LM_ * D_;

  int ls = tid & 63;
  int kk = ((ls >> 5) & 1) * 8;   // k-subgroup of 8 within the 16-wide step

  f32x16 acc[2][4];
  #pragma unroll
  for (int rt = 0; rt < 2; rt++)
    #pragma unroll
    for (int mtl = 0; mtl < 4; mtl++)
      #pragma unroll
      for (int j = 0; j < 16; j++) acc[rt][mtl][j] = 0.f;

  float4 stB[4][2];
  float4 stA[2];

  auto stage_load = [&](int k0) {
    #pragma unroll
    for (int i = 0; i < 4; i++) {
      int mt = (tid >> 6) + 4 * i;
      int m = 32 * mt + (ls & 31);
      const float* src = Mg + (size_t)m * D_ + k0 + kk;
      stB[i][0] = *(const float4*)src;
      stB[i][1] = *(const float4*)(src + 4);
    }
    if (tid < 128) {
      int rt = tid >> 6;
      int row = 32 * rt + (ls & 31);
      const float* src = Cg + (size_t)row * D_ + k0 + kk;
      stA[0] = *(const float4*)src;
      stA[1] = *(const float4*)(src + 4);
    }
  };

  auto cvt_write = [&](const float4& f0, const float4& f1, short* dh, short* dl) {
    float xs[8] = {f0.x, f0.y, f0.z, f0.w, f1.x, f1.y, f1.z, f1.w};
    short8 vh, vl;
    #pragma unroll
    for (int e = 0; e < 8; e++) {
      unsigned short hb = bf16_rn(xs[e]);
      float hf = __uint_as_float((unsigned)hb << 16);
      vh[e] = (short)hb;
      vl[e] = (short)bf16_rn(xs[e] - hf);
    }
    *(short8*)dh = vh;
    *(short8*)dl = vl;
  };

  auto stage_store = [&](int buf) {
    #pragma unroll
    for (int i = 0; i < 4; i++) {
      int mt = (tid >> 6) + 4 * i;
      int off = (mt * 64 + ls) * 8;
      cvt_write(stB[i][0], stB[i][1], &sm.Bf[buf][0][off], &sm.Bf[buf][1][off]);
    }
    if (tid < 128) {
      int rt = tid >> 6;
      int off = (rt * 64 + ls) * 8;
      cvt_write(stA[0], stA[1], &sm.Af[buf][0][off], &sm.Af[buf][1][off]);
    }
  };

  stage_load(0);
  stage_store(0);
  __syncthreads();

  for (int ks = 0; ks < 32; ks++) {
    int buf = ks & 1;
    if (ks < 31) stage_load((ks + 1) * 16);   // issue next-step globals early
    const short8* pAh = (const short8*)&sm.Af[buf][0][0];
    const short8* pAl = (const short8*)&sm.Af[buf][1][0];
    const short8* pBh = (const short8*)&sm.Bf[buf][0][0];
    const short8* pBl = (const short8*)&sm.Bf[buf][1][0];
    short8 ah0 = pAh[lane], ah1 = pAh[64 + lane];
    short8 al0 = pAl[lane], al1 = pAl[64 + lane];
    #pragma unroll
    for (int mtl = 0; mtl < 4; mtl++) {
      int mt = 4 * w + mtl;
      short8 bh = pBh[mt * 64 + lane];
      short8 bl = pBl[mt * 64 + lane];
      acc[0][mtl] = __builtin_amdgcn_mfma_f32_32x32x16_bf16(ah0, bh, acc[0][mtl], 0, 0, 0);
      acc[0][mtl] = __builtin_amdgcn_mfma_f32_32x32x16_bf16(ah0, bl, acc[0][mtl], 0, 0, 0);
      acc[0][mtl] = __builtin_amdgcn_mfma_f32_32x32x16_bf16(al0, bh, acc[0][mtl], 0, 0, 0);
      acc[1][mtl] = __builtin_amdgcn_mfma_f32_32x32x16_bf16(ah1, bh, acc[1][mtl], 0, 0, 0);
      acc[1][mtl] = __builtin_amdgcn_mfma_f32_32x32x16_bf16(ah1, bl, acc[1][mtl], 0, 0, 0);
      acc[1][mtl] = __builtin_amdgcn_mfma_f32_32x32x16_bf16(al1, bh, acc[1][mtl], 0, 0, 0);
    }
    if (ks < 31) stage_store(buf ^ 1);
    __syncthreads();
  }

  // ---- fused softmax over m (512) per c-row; cross-wave combine in LDS ----
  float cmax[2][16];
  #pragma unroll
  for (int rt = 0; rt < 2; rt++)
    #pragma unroll
    for (int j = 0; j < 16; j++) {
      float v = fmaxf(fmaxf(acc[rt][0][j], acc[rt][1][j]),
                      fmaxf(acc[rt][2][j], acc[rt][3][j]));
      #pragma unroll
      for (int s = 1; s < 32; s <<= 1) v = fmaxf(v, __shfl_xor(v, s, 64));
      cmax[rt][j] = v;
    }
  if ((lane & 31) == 0) {
    #pragma unroll
    for (int rt = 0; rt < 2; rt++)
      #pragma unroll
      for (int j = 0; j < 16; j++)
        sm.red[w][32 * rt + (j & 3) + 8 * (j >> 2) + 4 * h] = cmax[rt][j];
  }
  __syncthreads();
  if (tid < 64)
    sm.cmb[tid] = fmaxf(fmaxf(sm.red[0][tid], sm.red[1][tid]),
                        fmaxf(sm.red[2][tid], sm.red[3][tid]));
  __syncthreads();
  #pragma unroll
  for (int rt = 0; rt < 2; rt++)
    #pragma unroll
    for (int j = 0; j < 16; j++)
      cmax[rt][j] = sm.cmb[32 * rt + (j & 3) + 8 * (j >> 2) + 4 * h];

  float rsum[2][16];
  #pragma unroll
  for (int rt = 0; rt < 2; rt++)
    #pragma unroll
    for (int j = 0; j < 16; j++) {
      float s = 0.f;
      #pragma unroll
      for (int mtl = 0; mtl < 4; mtl++) {
        float e = __expf(acc[rt][mtl][j] - cmax[rt][j]);
        acc[rt][mtl][j] = e;
        s += e;
      }
      #pragma unroll
      for (int st = 1; st < 32; st <<= 1) s += __shfl_xor(s, st, 64);
      rsum[rt][j] = s;
    }
  if ((lane & 31) == 0) {
    #pragma unroll
    for (int rt = 0; rt < 2; rt++)
      #pragma unroll
      for (int j = 0; j < 16; j++)
        sm.red[w][32 * rt + (j & 3) + 8 * (j >> 2) + 4 * h] = rsum[rt][j];
  }
  __syncthreads();
  if (tid < 64)
    sm.cmb[tid] = sm.red[0][tid] + sm.red[1][tid] + sm.red[2][tid] + sm.red[3][tid];
  __syncthreads();

  float* Pb = P + ((size_t)b * LC_ + c0) * LM_;
  #pragma unroll
  for (int rt = 0; rt < 2; rt++)
    #pragma unroll
    for (int j = 0; j < 16; j++) {
      int row = 32 * rt + (j & 3) + 8 * (j >> 2) + 4 * h;
      float rinv = 1.f / sm.cmb[row];
      #pragma unroll
      for (int mtl = 0; mtl < 4; mtl++) {
        int col = 128 * w + 32 * mtl + (lane & 31);
        Pb[(size_t)row * LM_ + col] = acc[rt][mtl][j] * rinv;
      }
    }
}

// ---------------- K2: t[b,m] = v[b,m] - sum_c P[b,c,m]*u[b,c] --------------
__global__ __launch_bounds__(256) void k_t(const float* __restrict__ P,
                                           const float* __restrict__ u,
                                           const float* __restrict__ v,
                                           float* __restrict__ t) {
  int b = blockIdx.y;
  int m0 = blockIdx.x * 64;
  int tm = threadIdx.x & 63;
  int tg = threadIdx.x >> 6;
  const float* Pb = P + (size_t)b * LC_ * LM_ + m0;
  const float* ub = u + b * LC_;
  float acc = 0.f;
  #pragma unroll 4
  for (int c = tg; c < LC_; c += 4)
    acc += Pb[(size_t)c * LM_ + tm] * ub[c];
  __shared__ float red[4][64];
  red[tg][tm] = acc;
  __syncthreads();
  if (tg == 0) {
    float s = red[0][tm] + red[1][tm] + red[2][tm] + red[3][tm];
    t[b * LM_ + m0 + tm] = v[b * LM_ + m0 + tm] - s;
  }
}

// ---------------- K3: w[b,:] = softmax_m(t[b,:]) ---------------------------
__global__ __launch_bounds__(256) void k_w(const float* __restrict__ t,
                                           float* __restrict__ w) {
  int b = blockIdx.x;
  int tid = threadIdx.x;
  const float* tb = t + b * LM_;
  float2 x = *(const float2*)&tb[tid * 2];
  float mx = fmaxf(x.x, x.y);
  #pragma unroll
  for (int s = 32; s >= 1; s >>= 1) mx = fmaxf(mx, __shfl_xor(mx, s, 64));
  __shared__ float redm[4], reds[4];
  int wv = tid >> 6, ln = tid & 63;
  if (ln == 0) redm[wv] = mx;
  __syncthreads();
  mx = fmaxf(fmaxf(redm[0], redm[1]), fmaxf(redm[2], redm[3]));
  float e0 = __expf(x.x - mx), e1 = __expf(x.y - mx);
  float sum = e0 + e1;
  #pragma unroll
  for (int s = 32; s >= 1; s >>= 1) sum += __shfl_xor(sum, s, 64);
  if (ln == 0) reds[wv] = sum;
  __syncthreads();
  sum = reds[0] + reds[1] + reds[2] + reds[3];
  float rinv = 1.0f / sum;
  float2 o; o.x = e0 * rinv; o.y = e1 * rinv;
  *(float2*)&w[b * LM_ + tid * 2] = o;
}

// ---------------- K4: q[b,c] = sum_m P[b,c,m]*w[b,m] -----------------------
__global__ __launch_bounds__(256) void k_q(const float* __restrict__ P,
                                           const float* __restrict__ w,
                                           float* __restrict__ q) {
  int b = blockIdx.y;
  int c0 = blockIdx.x * 32;
  int wv = threadIdx.x >> 6, ln = threadIdx.x & 63;
  __shared__ float sw[LM_];
  *(float2*)&sw[threadIdx.x * 2] = *(const float2*)&w[b * LM_ + threadIdx.x * 2];
  __syncthreads();
  #pragma unroll
  for (int rr = 0; rr < 8; rr++) {
    int c = c0 + wv * 8 + rr;
    const float4* Pr = (const float4*)(P + ((size_t)b * LC_ + c) * LM_) + ln * 2;
    float4 p0 = Pr[0], p1 = Pr[1];
    const float4* wr = (const float4*)sw + ln * 2;
    float4 w0 = wr[0], w1 = wr[1];
    float acc = p0.x*w0.x + p0.y*w0.y + p0.z*w0.z + p0.w*w0.w
              + p1.x*w1.x + p1.y*w1.y + p1.z*w1.z + p1.w*w1.w;
    #pragma unroll
    for (int s = 32; s >= 1; s >>= 1) acc += __shfl_xor(acc, s, 64);
    if (ln == 0) q[b * LC_ + c] = acc;
  }
}

// ---------------- K5: out[b,d] = sum_m w*main - sum_c q*ctx ----------------
__global__ __launch_bounds__(256) void k_out(const float* __restrict__ ctx,
                                             const float* __restrict__ mn,
                                             const float* __restrict__ w,
                                             const float* __restrict__ q,
                                             float* __restrict__ out) {
  int b = blockIdx.y;
  int d0 = blockIdx.x * 64;
  int td = threadIdx.x & 63;
  int tg = threadIdx.x >> 6;
  const float* Mb = mn  + (size_t)b * LM_ * D_ + d0;
  const float* Cb = ctx + (size_t)b * LC_ * D_ + d0;
  const float* wb = w + b * LM_;
  const float* qb = q + b * LC_;
  float acc = 0.f;
  #pragma unroll 4
  for (int m = tg; m < LM_; m += 4) acc += wb[m] * Mb[(size_t)m * D_ + td];
  #pragma unroll 4
  for (int c = tg; c < LC_; c += 4) acc -= qb[c] * Cb[(size_t)c * D_ + td];
  __shared__ float red[4][64];
  red[tg][td] = acc;
  __syncthreads();
  if (tg == 0)
    out[b * D_ + d0 + td] = red[0][td] + red[1][td] + red[2][td] + red[3][td];
}

extern "C" void kernel_launch(void* const* d_in, const int* in_sizes, int n_in,
                              void* d_out, int out_size, void* d_ws, size_t ws_size,
                              hipStream_t stream) {
  const float* ctx = (const float*)d_in[0];
  const float* mn  = (const float*)d_in[1];
  const float* W   = (const float*)d_in[2];
  float* out = (float*)d_out;

  float* ws = (float*)d_ws;
  size_t nP = (size_t)B_ * LC_ * LM_;          // 134.2 MB
  float* P = ws;
  float* u = ws + nP;
  float* v = u + (size_t)B_ * LC_;
  float* t = v + (size_t)B_ * LM_;
  float* w = t + (size_t)B_ * LM_;
  float* q = w + (size_t)B_ * LM_;

  k_uv<<<dim3(B_ * 1024 / 4), 256, 0, stream>>>(ctx, mn, W, u, v);
  k_scores_mfma<<<dim3(LC_ / 64, B_), 256, 0, stream>>>(ctx, mn, P);
  k_t<<<dim3(LM_ / 64, B_), 256, 0, stream>>>(P, u, v, t);
  k_w<<<dim3(B_), 256, 0, stream>>>(t, w);
  k_q<<<dim3(LC_ / 32, B_), 256, 0, stream>>>(P, w, q);
  k_out<<<dim3(D_ / 64, B_), 256, 0, stream>>>(ctx, mn, w, q, out);
}

// Round 6
// 395.369 us; speedup vs baseline: 2.4414x; 1.0341x over previous
//
#include <hip/hip_runtime.h>

#define B_  128
#define LC_ 512
#define LM_ 512
#define D_  512

typedef __attribute__((ext_vector_type(8))) short short8;
typedef __attribute__((ext_vector_type(16))) float f32x16;
typedef unsigned int u32;

__device__ __forceinline__ unsigned short bf16_rn(float x) {
  unsigned u = __float_as_uint(x);
  unsigned r = u + 0x7fffu + ((u >> 16) & 1u);
  return (unsigned short)(r >> 16);
}

__device__ __forceinline__ void gl_lds16(const void* g, void* l) {
  __builtin_amdgcn_global_load_lds((const __attribute__((address_space(1))) u32*)g,
                                   (__attribute__((address_space(3))) u32*)l, 16, 0, 0);
}

// =====================  NEW PATH  ==========================================
// k_cvt_uv: stream ctx/main once; emit bf16 hi/lo planes + u,v dots.
__global__ __launch_bounds__(256) void k_cvt_uv(
    const float* __restrict__ ctx, const float* __restrict__ mn,
    const float* __restrict__ W,
    short* __restrict__ ctxH, short* __restrict__ ctxL,
    short* __restrict__ mnH, short* __restrict__ mnL,
    float* __restrict__ u, float* __restrict__ v) {
  int wave = blockIdx.x * 4 + (threadIdx.x >> 6);
  int lane = threadIdx.x & 63;
  int b = wave >> 10;
  int r = wave & 1023;
  const float* src; short *dH, *dL; float* ds;
  if (r < LC_) {
    size_t ro = ((size_t)b * LC_ + r) * D_;
    src = ctx + ro; dH = ctxH + ro; dL = ctxL + ro; ds = u + b * LC_ + r;
  } else {
    r -= LC_;
    size_t ro = ((size_t)b * LM_ + r) * D_;
    src = mn + ro; dH = mnH + ro; dL = mnL + ro; ds = v + b * LM_ + r;
  }
  float4 a0 = *(const float4*)(src + lane * 8);
  float4 a1 = *(const float4*)(src + lane * 8 + 4);
  float4 w0 = *(const float4*)(W + lane * 8);
  float4 w1 = *(const float4*)(W + lane * 8 + 4);
  float xs[8] = {a0.x, a0.y, a0.z, a0.w, a1.x, a1.y, a1.z, a1.w};
  float wv[8] = {w0.x, w0.y, w0.z, w0.w, w1.x, w1.y, w1.z, w1.w};
  short8 vh, vl;
  float acc = 0.f;
  #pragma unroll
  for (int e = 0; e < 8; e++) {
    unsigned short hb = bf16_rn(xs[e]);
    float hf = __uint_as_float((unsigned)hb << 16);
    vh[e] = (short)hb;
    vl[e] = (short)bf16_rn(xs[e] - hf);
    acc = fmaf(xs[e], wv[e], acc);
  }
  *(short8*)(dH + lane * 8) = vh;
  *(short8*)(dL + lane * 8) = vl;
  #pragma unroll
  for (int s = 32; s >= 1; s >>= 1) acc += __shfl_xor(acc, s, 64);
  if (lane == 0) *ds = acc;
}

// k_scores_mfma2: pure dual-plane bf16 GEMM (3-term split) + fused softmax +
// fused t-partials. gload_lds staging, fragment-ordered LDS, XCD swizzle.
struct __align__(16) Smem2 {
  short8 Bf[2][2][16][64];   // [buf][plane][mt][lane]  64 KB
  short8 Af[2][2][2][64];    // [buf][plane][rt][lane]   8 KB
  float red[4][64];
  float cmb[64];
  float uld[64];
};

__global__ __launch_bounds__(256, 2) void k_scores_mfma2(
    const short* __restrict__ ctxH, const short* __restrict__ ctxL,
    const short* __restrict__ mnH, const short* __restrict__ mnL,
    const float* __restrict__ u,
    float* __restrict__ P, float* __restrict__ tpart) {
  __shared__ Smem2 sm;
  int wg = blockIdx.x;
  int swz = (wg & 7) * 128 + (wg >> 3);   // 8 c-blocks of a batch -> same XCD
  int b = swz >> 3, cblk = swz & 7;
  int c0 = cblk * 64;
  int tid = threadIdx.x, lane = tid & 63, w = tid >> 6, h = lane >> 5;
  int rowl = lane & 31, kh = h * 8;

  const short* Ag0 = ctxH + ((size_t)b * LC_ + c0) * D_;
  const short* Ag1 = ctxL + ((size_t)b * LC_ + c0) * D_;
  const short* Bg0 = mnH + (size_t)b * LM_ * D_;
  const short* Bg1 = mnL + (size_t)b * LM_ * D_;

  f32x16 acc[2][4];
  #pragma unroll
  for (int rt = 0; rt < 2; rt++)
    #pragma unroll
    for (int mtl = 0; mtl < 4; mtl++)
      #pragma unroll
      for (int j = 0; j < 16; j++) acc[rt][mtl][j] = 0.f;

  auto stage = [&](int buf, int k0) {
    #pragma unroll
    for (int i = 0; i < 4; i++) {
      int mt = w + 4 * i;
      size_t go = (size_t)(32 * mt + rowl) * D_ + k0 + kh;
      gl_lds16(Bg0 + go, &sm.Bf[buf][0][mt][0]);
      gl_lds16(Bg1 + go, &sm.Bf[buf][1][mt][0]);
    }
    int rt = w >> 1;
    size_t ga = (size_t)(32 * rt + rowl) * D_ + k0 + kh;
    const short* Ap = (w & 1) ? Ag1 : Ag0;
    gl_lds16(Ap + ga, &sm.Af[buf][w & 1][rt][0]);
  };

  stage(0, 0);
  __syncthreads();

  for (int ks = 0; ks < 32; ks++) {
    int buf = ks & 1;
    if (ks < 31) stage(buf ^ 1, (ks + 1) * 16);
    short8 ah0 = sm.Af[buf][0][0][lane], ah1 = sm.Af[buf][0][1][lane];
    short8 al0 = sm.Af[buf][1][0][lane], al1 = sm.Af[buf][1][1][lane];
    #pragma unroll
    for (int mtl = 0; mtl < 4; mtl++) {
      int mt = 4 * w + mtl;
      short8 bh = sm.Bf[buf][0][mt][lane];
      short8 bl = sm.Bf[buf][1][mt][lane];
      acc[0][mtl] = __builtin_amdgcn_mfma_f32_32x32x16_bf16(ah0, bh, acc[0][mtl], 0, 0, 0);
      acc[0][mtl] = __builtin_amdgcn_mfma_f32_32x32x16_bf16(ah0, bl, acc[0][mtl], 0, 0, 0);
      acc[0][mtl] = __builtin_amdgcn_mfma_f32_32x32x16_bf16(al0, bh, acc[0][mtl], 0, 0, 0);
      acc[1][mtl] = __builtin_amdgcn_mfma_f32_32x32x16_bf16(ah1, bh, acc[1][mtl], 0, 0, 0);
      acc[1][mtl] = __builtin_amdgcn_mfma_f32_32x32x16_bf16(ah1, bl, acc[1][mtl], 0, 0, 0);
      acc[1][mtl] = __builtin_amdgcn_mfma_f32_32x32x16_bf16(al1, bh, acc[1][mtl], 0, 0, 0);
    }
    __syncthreads();
  }

  if (tid < 64) sm.uld[tid] = u[b * LC_ + c0 + tid];

  // fused softmax over m (512) per c-row
  float cmax[2][16];
  #pragma unroll
  for (int rt = 0; rt < 2; rt++)
    #pragma unroll
    for (int j = 0; j < 16; j++) {
      float vv = fmaxf(fmaxf(acc[rt][0][j], acc[rt][1][j]),
                       fmaxf(acc[rt][2][j], acc[rt][3][j]));
      #pragma unroll
      for (int s = 1; s < 32; s <<= 1) vv = fmaxf(vv, __shfl_xor(vv, s, 64));
      cmax[rt][j] = vv;
    }
  if ((lane & 31) == 0) {
    #pragma unroll
    for (int rt = 0; rt < 2; rt++)
      #pragma unroll
      for (int j = 0; j < 16; j++)
        sm.red[w][32 * rt + (j & 3) + 8 * (j >> 2) + 4 * h] = cmax[rt][j];
  }
  __syncthreads();
  if (tid < 64)
    sm.cmb[tid] = fmaxf(fmaxf(sm.red[0][tid], sm.red[1][tid]),
                        fmaxf(sm.red[2][tid], sm.red[3][tid]));
  __syncthreads();
  #pragma unroll
  for (int rt = 0; rt < 2; rt++)
    #pragma unroll
    for (int j = 0; j < 16; j++)
      cmax[rt][j] = sm.cmb[32 * rt + (j & 3) + 8 * (j >> 2) + 4 * h];

  float rsum[2][16];
  #pragma unroll
  for (int rt = 0; rt < 2; rt++)
    #pragma unroll
    for (int j = 0; j < 16; j++) {
      float s = 0.f;
      #pragma unroll
      for (int mtl = 0; mtl < 4; mtl++) {
        float e = __expf(acc[rt][mtl][j] - cmax[rt][j]);
        acc[rt][mtl][j] = e;
        s += e;
      }
      #pragma unroll
      for (int st = 1; st < 32; st <<= 1) s += __shfl_xor(s, st, 64);
      rsum[rt][j] = s;
    }
  if ((lane & 31) == 0) {
    #pragma unroll
    for (int rt = 0; rt < 2; rt++)
      #pragma unroll
      for (int j = 0; j < 16; j++)
        sm.red[w][32 * rt + (j & 3) + 8 * (j >> 2) + 4 * h] = rsum[rt][j];
  }
  __syncthreads();
  if (tid < 64)
    sm.cmb[tid] = sm.red[0][tid] + sm.red[1][tid] + sm.red[2][tid] + sm.red[3][tid];
  __syncthreads();

  float* Pb = P + ((size_t)b * LC_ + c0) * LM_;
  float tp[4] = {0.f, 0.f, 0.f, 0.f};
  #pragma unroll
  for (int rt = 0; rt < 2; rt++)
    #pragma unroll
    for (int j = 0; j < 16; j++) {
      int row = 32 * rt + (j & 3) + 8 * (j >> 2) + 4 * h;
      float rinv = 1.f / sm.cmb[row];
      float uu = sm.uld[row];
      #pragma unroll
      for (int mtl = 0; mtl < 4; mtl++) {
        float pv = acc[rt][mtl][j] * rinv;
        Pb[(size_t)row * LM_ + 128 * w + 32 * mtl + rowl] = pv;
        tp[mtl] = fmaf(pv, uu, tp[mtl]);
      }
    }
  #pragma unroll
  for (int mtl = 0; mtl < 4; mtl++) tp[mtl] += __shfl_xor(tp[mtl], 32, 64);
  if (h == 0) {
    float* tpb = tpart + ((size_t)b * 8 + cblk) * LM_;
    #pragma unroll
    for (int mtl = 0; mtl < 4; mtl++)
      tpb[128 * w + 32 * mtl + rowl] = tp[mtl];
  }
}

// k_tw: t = v - sum(tpart); w = softmax(t). One block per batch.
__global__ __launch_bounds__(256) void k_tw(const float* __restrict__ tpart,
                                            const float* __restrict__ v,
                                            float* __restrict__ w_) {
  int b = blockIdx.x;
  int tid = threadIdx.x;
  int m0 = tid * 2;
  const float* tp = tpart + (size_t)b * 8 * LM_;
  float s0 = 0.f, s1 = 0.f;
  #pragma unroll
  for (int cb = 0; cb < 8; cb++) {
    s0 += tp[cb * LM_ + m0];
    s1 += tp[cb * LM_ + m0 + 1];
  }
  float x0 = v[b * LM_ + m0] - s0;
  float x1 = v[b * LM_ + m0 + 1] - s1;
  float mx = fmaxf(x0, x1);
  #pragma unroll
  for (int s = 32; s >= 1; s >>= 1) mx = fmaxf(mx, __shfl_xor(mx, s, 64));
  __shared__ float redm[4], reds[4];
  int wv = tid >> 6, ln = tid & 63;
  if (ln == 0) redm[wv] = mx;
  __syncthreads();
  mx = fmaxf(fmaxf(redm[0], redm[1]), fmaxf(redm[2], redm[3]));
  float e0 = __expf(x0 - mx), e1 = __expf(x1 - mx);
  float sum = e0 + e1;
  #pragma unroll
  for (int s = 32; s >= 1; s >>= 1) sum += __shfl_xor(sum, s, 64);
  if (ln == 0) reds[wv] = sum;
  __syncthreads();
  sum = reds[0] + reds[1] + reds[2] + reds[3];
  float rinv = 1.0f / sum;
  float2 o; o.x = e0 * rinv; o.y = e1 * rinv;
  *(float2*)&w_[b * LM_ + m0] = o;
}

// =====================  SHARED (both paths)  ===============================
__global__ __launch_bounds__(256) void k_q(const float* __restrict__ P,
                                           const float* __restrict__ w,
                                           float* __restrict__ q) {
  int b = blockIdx.y;
  int c0 = blockIdx.x * 32;
  int wv = threadIdx.x >> 6, ln = threadIdx.x & 63;
  __shared__ float sw[LM_];
  *(float2*)&sw[threadIdx.x * 2] = *(const float2*)&w[b * LM_ + threadIdx.x * 2];
  __syncthreads();
  #pragma unroll
  for (int rr = 0; rr < 8; rr++) {
    int c = c0 + wv * 8 + rr;
    const float4* Pr = (const float4*)(P + ((size_t)b * LC_ + c) * LM_) + ln * 2;
    float4 p0 = Pr[0], p1 = Pr[1];
    const float4* wr = (const float4*)sw + ln * 2;
    float4 w0 = wr[0], w1 = wr[1];
    float acc = p0.x*w0.x + p0.y*w0.y + p0.z*w0.z + p0.w*w0.w
              + p1.x*w1.x + p1.y*w1.y + p1.z*w1.z + p1.w*w1.w;
    #pragma unroll
    for (int s = 32; s >= 1; s >>= 1) acc += __shfl_xor(acc, s, 64);
    if (ln == 0) q[b * LC_ + c] = acc;
  }
}

__global__ __launch_bounds__(256) void k_out(const float* __restrict__ ctx,
                                             const float* __restrict__ mn,
                                             const float* __restrict__ w,
                                             const float* __restrict__ q,
                                             float* __restrict__ out) {
  int b = blockIdx.y;
  int d0 = blockIdx.x * 64;
  int td = threadIdx.x & 63;
  int tg = threadIdx.x >> 6;
  const float* Mb = mn  + (size_t)b * LM_ * D_ + d0;
  const float* Cb = ctx + (size_t)b * LC_ * D_ + d0;
  const float* wb = w + b * LM_;
  const float* qb = q + b * LC_;
  float acc = 0.f;
  #pragma unroll 4
  for (int m = tg; m < LM_; m += 4) acc += wb[m] * Mb[(size_t)m * D_ + td];
  #pragma unroll 4
  for (int c = tg; c < LC_; c += 4) acc -= qb[c] * Cb[(size_t)c * D_ + td];
  __shared__ float red[4][64];
  red[tg][td] = acc;
  __syncthreads();
  if (tg == 0)
    out[b * D_ + d0 + td] = red[0][td] + red[1][td] + red[2][td] + red[3][td];
}

// =====================  OLD PATH (R5 fallback, ws-limited)  ================
__global__ __launch_bounds__(256) void k_uv(const float* __restrict__ ctx,
                                            const float* __restrict__ mn,
                                            const float* __restrict__ W,
                                            float* __restrict__ u,
                                            float* __restrict__ v) {
  int wave = blockIdx.x * 4 + (threadIdx.x >> 6);
  int lane = threadIdx.x & 63;
  int b = wave >> 10;
  int r = wave & 1023;
  const float* src;
  float* dst;
  if (r < LC_) { src = ctx + ((size_t)b * LC_ + r) * D_; dst = u + b * LC_ + r; }
  else { r -= LC_; src = mn + ((size_t)b * LM_ + r) * D_; dst = v + b * LM_ + r; }
  const float4* s4 = (const float4*)src + lane * 2;
  const float4* w4 = (const float4*)W   + lane * 2;
  float4 a0 = s4[0], a1 = s4[1];
  float4 b0 = w4[0], b1 = w4[1];
  float acc = a0.x*b0.x + a0.y*b0.y + a0.z*b0.z + a0.w*b0.w
            + a1.x*b1.x + a1.y*b1.y + a1.z*b1.z + a1.w*b1.w;
  #pragma unroll
  for (int s = 32; s >= 1; s >>= 1) acc += __shfl_xor(acc, s, 64);
  if (lane == 0) *dst = acc;
}

struct __align__(16) Smem1 {
  short Bf[2][2][16 * 64 * 8];
  short Af[2][2][2 * 64 * 8];
  float red[4][64];
  float cmb[64];
};

__global__ __launch_bounds__(256, 2) void k_scores_mfma_v1(
    const float* __restrict__ ctx, const float* __restrict__ mn,
    float* __restrict__ P) {
  __shared__ Smem1 sm;
  int b   = blockIdx.y;
  int c0  = blockIdx.x * 64;
  int tid = threadIdx.x;
  int lane = tid & 63;
  int w = tid >> 6;
  int h = lane >> 5;
  const float* Cg = ctx + ((size_t)b * LC_ + c0) * D_;
  const float* Mg = mn + (size_t)b * LM_ * D_;
  int ls = tid & 63;
  int kk = ((ls >> 5) & 1) * 8;
  f32x16 acc[2][4];
  #pragma unroll
  for (int rt = 0; rt < 2; rt++)
    #pragma unroll
    for (int mtl = 0; mtl < 4; mtl++)
      #pragma unroll
      for (int j = 0; j < 16; j++) acc[rt][mtl][j] = 0.f;
  float4 stB[4][2];
  float4 stA[2];
  auto stage_load = [&](int k0) {
    #pragma unroll
    for (int i = 0; i < 4; i++) {
      int mt = (tid >> 6) + 4 * i;
      int m = 32 * mt + (ls & 31);
      const float* src = Mg + (size_t)m * D_ + k0 + kk;
      stB[i][0] = *(const float4*)src;
      stB[i][1] = *(const float4*)(src + 4);
    }
    if (tid < 128) {
      int rt = tid >> 6;
      int row = 32 * rt + (ls & 31);
      const float* src = Cg + (size_t)row * D_ + k0 + kk;
      stA[0] = *(const float4*)src;
      stA[1] = *(const float4*)(src + 4);
    }
  };
  auto cvt_write = [&](const float4& f0, const float4& f1, short* dh, short* dl) {
    float xs[8] = {f0.x, f0.y, f0.z, f0.w, f1.x, f1.y, f1.z, f1.w};
    short8 vh, vl;
    #pragma unroll
    for (int e = 0; e < 8; e++) {
      unsigned short hb = bf16_rn(xs[e]);
      float hf = __uint_as_float((unsigned)hb << 16);
      vh[e] = (short)hb;
      vl[e] = (short)bf16_rn(xs[e] - hf);
    }
    *(short8*)dh = vh;
    *(short8*)dl = vl;
  };
  auto stage_store = [&](int buf) {
    #pragma unroll
    for (int i = 0; i < 4; i++) {
      int mt = (tid >> 6) + 4 * i;
      int off = (mt * 64 + ls) * 8;
      cvt_write(stB[i][0], stB[i][1], &sm.Bf[buf][0][off], &sm.Bf[buf][1][off]);
    }
    if (tid < 128) {
      int rt = tid >> 6;
      int off = (rt * 64 + ls) * 8;
      cvt_write(stA[0], stA[1], &sm.Af[buf][0][off], &sm.Af[buf][1][off]);
    }
  };
  stage_load(0);
  stage_store(0);
  __syncthreads();
  for (int ks = 0; ks < 32; ks++) {
    int buf = ks & 1;
    if (ks < 31) stage_load((ks + 1) * 16);
    const short8* pAh = (const short8*)&sm.Af[buf][0][0];
    const short8* pAl = (const short8*)&sm.Af[buf][1][0];
    const short8* pBh = (const short8*)&sm.Bf[buf][0][0];
    const short8* pBl = (const short8*)&sm.Bf[buf][1][0];
    short8 ah0 = pAh[lane], ah1 = pAh[64 + lane];
    short8 al0 = pAl[lane], al1 = pAl[64 + lane];
    #pragma unroll
    for (int mtl = 0; mtl < 4; mtl++) {
      int mt = 4 * w + mtl;
      short8 bh = pBh[mt * 64 + lane];
      short8 bl = pBl[mt * 64 + lane];
      acc[0][mtl] = __builtin_amdgcn_mfma_f32_32x32x16_bf16(ah0, bh, acc[0][mtl], 0, 0, 0);
      acc[0][mtl] = __builtin_amdgcn_mfma_f32_32x32x16_bf16(ah0, bl, acc[0][mtl], 0, 0, 0);
      acc[0][mtl] = __builtin_amdgcn_mfma_f32_32x32x16_bf16(al0, bh, acc[0][mtl], 0, 0, 0);
      acc[1][mtl] = __builtin_amdgcn_mfma_f32_32x32x16_bf16(ah1, bh, acc[1][mtl], 0, 0, 0);
      acc[1][mtl] = __builtin_amdgcn_mfma_f32_32x32x16_bf16(ah1, bl, acc[1][mtl], 0, 0, 0);
      acc[1][mtl] = __builtin_amdgcn_mfma_f32_32x32x16_bf16(al1, bh, acc[1][mtl], 0, 0, 0);
    }
    if (ks < 31) stage_store(buf ^ 1);
    __syncthreads();
  }
  float cmax[2][16];
  #pragma unroll
  for (int rt = 0; rt < 2; rt++)
    #pragma unroll
    for (int j = 0; j < 16; j++) {
      float v = fmaxf(fmaxf(acc[rt][0][j], acc[rt][1][j]),
                      fmaxf(acc[rt][2][j], acc[rt][3][j]));
      #pragma unroll
      for (int s = 1; s < 32; s <<= 1) v = fmaxf(v, __shfl_xor(v, s, 64));
      cmax[rt][j] = v;
    }
  if ((lane & 31) == 0) {
    #pragma unroll
    for (int rt = 0; rt < 2; rt++)
      #pragma unroll
      for (int j = 0; j < 16; j++)
        sm.red[w][32 * rt + (j & 3) + 8 * (j >> 2) + 4 * h] = cmax[rt][j];
  }
  __syncthreads();
  if (tid < 64)
    sm.cmb[tid] = fmaxf(fmaxf(sm.red[0][tid], sm.red[1][tid]),
                        fmaxf(sm.red[2][tid], sm.red[3][tid]));
  __syncthreads();
  #pragma unroll
  for (int rt = 0; rt < 2; rt++)
    #pragma unroll
    for (int j = 0; j < 16; j++)
      cmax[rt][j] = sm.cmb[32 * rt + (j & 3) + 8 * (j >> 2) + 4 * h];
  float rsum[2][16];
  #pragma unroll
  for (int rt = 0; rt < 2; rt++)
    #pragma unroll
    for (int j = 0; j < 16; j++) {
      float s = 0.f;
      #pragma unroll
      for (int mtl = 0; mtl < 4; mtl++) {
        float e = __expf(acc[rt][mtl][j] - cmax[rt][j]);
        acc[rt][mtl][j] = e;
        s += e;
      }
      #pragma unroll
      for (int st = 1; st < 32; st <<= 1) s += __shfl_xor(s, st, 64);
      rsum[rt][j] = s;
    }
  if ((lane & 31) == 0) {
    #pragma unroll
    for (int rt = 0; rt < 2; rt++)
      #pragma unroll
      for (int j = 0; j < 16; j++)
        sm.red[w][32 * rt + (j & 3) + 8 * (j >> 2) + 4 * h] = rsum[rt][j];
  }
  __syncthreads();
  if (tid < 64)
    sm.cmb[tid] = sm.red[0][tid] + sm.red[1][tid] + sm.red[2][tid] + sm.red[3][tid];
  __syncthreads();
  float* Pb = P + ((size_t)b * LC_ + c0) * LM_;
  #pragma unroll
  for (int rt = 0; rt < 2; rt++)
    #pragma unroll
    for (int j = 0; j < 16; j++) {
      int row = 32 * rt + (j & 3) + 8 * (j >> 2) + 4 * h;
      float rinv = 1.f / sm.cmb[row];
      #pragma unroll
      for (int mtl = 0; mtl < 4; mtl++) {
        int col = 128 * w + 32 * mtl + (lane & 31);
        Pb[(size_t)row * LM_ + col] = acc[rt][mtl][j] * rinv;
      }
    }
}

__global__ __launch_bounds__(256) void k_t(const float* __restrict__ P,
                                           const float* __restrict__ u,
                                           const float* __restrict__ v,
                                           float* __restrict__ t) {
  int b = blockIdx.y;
  int m0 = blockIdx.x * 64;
  int tm = threadIdx.x & 63;
  int tg = threadIdx.x >> 6;
  const float* Pb = P + (size_t)b * LC_ * LM_ + m0;
  const float* ub = u + b * LC_;
  float acc = 0.f;
  #pragma unroll 4
  for (int c = tg; c < LC_; c += 4)
    acc += Pb[(size_t)c * LM_ + tm] * ub[c];
  __shared__ float red[4][64];
  red[tg][tm] = acc;
  __syncthreads();
  if (tg == 0) {
    float s = red[0][tm] + red[1][tm] + red[2][tm] + red[3][tm];
    t[b * LM_ + m0 + tm] = v[b * LM_ + m0 + tm] - s;
  }
}

__global__ __launch_bounds__(256) void k_w(const float* __restrict__ t,
                                           float* __restrict__ w) {
  int b = blockIdx.x;
  int tid = threadIdx.x;
  const float* tb = t + b * LM_;
  float2 x = *(const float2*)&tb[tid * 2];
  float mx = fmaxf(x.x, x.y);
  #pragma unroll
  for (int s = 32; s >= 1; s >>= 1) mx = fmaxf(mx, __shfl_xor(mx, s, 64));
  __shared__ float redm[4], reds[4];
  int wv = tid >> 6, ln = tid & 63;
  if (ln == 0) redm[wv] = mx;
  __syncthreads();
  mx = fmaxf(fmaxf(redm[0], redm[1]), fmaxf(redm[2], redm[3]));
  float e0 = __expf(x.x - mx), e1 = __expf(x.y - mx);
  float sum = e0 + e1;
  #pragma unroll
  for (int s = 32; s >= 1; s >>= 1) sum += __shfl_xor(sum, s, 64);
  if (ln == 0) reds[wv] = sum;
  __syncthreads();
  sum = reds[0] + reds[1] + reds[2] + reds[3];
  float rinv = 1.0f / sum;
  float2 o; o.x = e0 * rinv; o.y = e1 * rinv;
  *(float2*)&w[b * LM_ + tid * 2] = o;
}

// =====================  LAUNCH  ============================================
extern "C" void kernel_launch(void* const* d_in, const int* in_sizes, int n_in,
                              void* d_out, int out_size, void* d_ws, size_t ws_size,
                              hipStream_t stream) {
  const float* ctx = (const float*)d_in[0];
  const float* mn  = (const float*)d_in[1];
  const float* W   = (const float*)d_in[2];
  float* out = (float*)d_out;

  char* base = (char*)d_ws;
  size_t nPbytes = (size_t)B_ * LC_ * LM_ * 4;          // 134,217,728
  size_t planeB  = (size_t)B_ * 512 * 512 * 2;          // 67,108,864 per plane

  size_t need_new = nPbytes + 4 * planeB + (size_t)B_ * 8 * LM_ * 4
                  + 4 * (size_t)B_ * 512 * 4;           // ~405.8 MB

  if (ws_size >= need_new) {
    float* P    = (float*)base;
    short* mnH  = (short*)(base + nPbytes);
    short* mnL  = (short*)(base + nPbytes + planeB);
    short* ctxH = (short*)(base + nPbytes + 2 * planeB);
    short* ctxL = (short*)(base + nPbytes + 3 * planeB);
    char*  p2   = base + nPbytes + 4 * planeB;
    float* tpart = (float*)p2;                           p2 += (size_t)B_ * 8 * LM_ * 4;
    float* u = (float*)p2;                               p2 += (size_t)B_ * LC_ * 4;
    float* v = (float*)p2;                               p2 += (size_t)B_ * LM_ * 4;
    float* w = (float*)p2;                               p2 += (size_t)B_ * LM_ * 4;
    float* q = (float*)p2;

    k_cvt_uv<<<dim3(B_ * 1024 / 4), 256, 0, stream>>>(ctx, mn, W, ctxH, ctxL, mnH, mnL, u, v);
    k_scores_mfma2<<<dim3(1024), 256, 0, stream>>>(ctxH, ctxL, mnH, mnL, u, P, tpart);
    k_tw<<<dim3(B_), 256, 0, stream>>>(tpart, v, w);
    k_q<<<dim3(LC_ / 32, B_), 256, 0, stream>>>(P, w, q);
    k_out<<<dim3(D_ / 64, B_), 256, 0, stream>>>(ctx, mn, w, q, out);
  } else {
    float* ws = (float*)d_ws;
    size_t nP = (size_t)B_ * LC_ * LM_;
    float* P = ws;
    float* u = ws + nP;
    float* v = u + (size_t)B_ * LC_;
    float* t = v + (size_t)B_ * LM_;
    float* w = t + (size_t)B_ * LM_;
    float* q = w + (size_t)B_ * LM_;

    k_uv<<<dim3(B_ * 1024 / 4), 256, 0, stream>>>(ctx, mn, W, u, v);
    k_scores_mfma_v1<<<dim3(LC_ / 64, B_), 256, 0, stream>>>(ctx, mn, P);
    k_t<<<dim3(LM_ / 64, B_), 256, 0, stream>>>(P, u, v, t);
    k_w<<<dim3(B_), 256, 0, stream>>>(t, w);
    k_q<<<dim3(LC_ / 32, B_), 256, 0, stream>>>(P, w, q);
    k_out<<<dim3(D_ / 64, B_), 256, 0, stream>>>(ctx, mn, w, q, out);
  }
}

// Round 7
// 281.795 us; speedup vs baseline: 3.4253x; 1.4030x over previous
//
#include <hip/hip_runtime.h>

#define B_  128
#define LC_ 512
#define LM_ 512
#define D_  512

typedef __attribute__((ext_vector_type(8))) short short8;
typedef __attribute__((ext_vector_type(16))) float f32x16;
typedef unsigned int u32;

__device__ __forceinline__ unsigned short bf16_rn(float x) {
  unsigned u = __float_as_uint(x);
  unsigned r = u + 0x7fffu + ((u >> 16) & 1u);
  return (unsigned short)(r >> 16);
}

__device__ __forceinline__ void gl_lds16(const void* g, void* l) {
  __builtin_amdgcn_global_load_lds((const __attribute__((address_space(1))) u32*)g,
                                   (__attribute__((address_space(3))) u32*)l, 16, 0, 0);
}

// ---------------- k_cvt_main: main fp32 -> tiled fragment-order bf16 planes
// Bt[b][ks][mt][lane][8]: row = 32*mt + (lane&31), k = 16*ks + (lane>>5)*8 + e.
// Also fused v[b,m] = main[b,m,:]·W (fp32). Wave = one (b, mt) tile.
__global__ __launch_bounds__(256) void k_cvt_main(
    const float* __restrict__ mn, const float* __restrict__ W,
    short* __restrict__ BtH, short* __restrict__ BtL,
    float* __restrict__ v) {
  __shared__ float sW[512];
  int tid = threadIdx.x;
  sW[tid] = W[tid];
  sW[tid + 256] = W[tid + 256];
  __syncthreads();
  int wave = blockIdx.x * 4 + (tid >> 6);
  int b = wave >> 4, mt = wave & 15;
  int lane = tid & 63, rowl = lane & 31, h = lane >> 5;
  const float* src = mn + ((size_t)b * LM_ + 32 * mt + rowl) * D_ + 8 * h;
  float acc = 0.f;
  for (int ks = 0; ks < 32; ks++) {
    float4 f0 = *(const float4*)(src + 16 * ks);
    float4 f1 = *(const float4*)(src + 16 * ks + 4);
    float xs[8] = {f0.x, f0.y, f0.z, f0.w, f1.x, f1.y, f1.z, f1.w};
    int k = 16 * ks + 8 * h;
    float4 w0 = *(const float4*)&sW[k];
    float4 w1 = *(const float4*)&sW[k + 4];
    float ws[8] = {w0.x, w0.y, w0.z, w0.w, w1.x, w1.y, w1.z, w1.w};
    short8 vh, vl;
    #pragma unroll
    for (int e = 0; e < 8; e++) {
      unsigned short hb = bf16_rn(xs[e]);
      float hf = __uint_as_float((unsigned)hb << 16);
      vh[e] = (short)hb;
      vl[e] = (short)bf16_rn(xs[e] - hf);
      acc = fmaf(xs[e], ws[e], acc);
    }
    size_t off = (((size_t)b * 32 + ks) * 16 + mt) * 512 + (size_t)lane * 8;
    *(short8*)(BtH + off) = vh;
    *(short8*)(BtL + off) = vl;
  }
  acc += __shfl_xor(acc, 32, 64);
  if (h == 0) v[b * LM_ + 32 * mt + rowl] = acc;
}

// ---------------- k_scores_mfma3: 128c x 512m block, 8 waves ---------------
// B staged via linear gl_lds from tiled planes; A converted in-kernel from
// fp32 (fused u = ctx·W); fused softmax + t-partials. 3-term split MFMA.
struct __align__(16) Smem3 {
  short8 Bf[2][2][16][64];   // [buf][pl][mt][lane]  64 KB
  short8 Af[2][2][4][64];    // [buf][pl][rt][lane]  16 KB
  float sW[512];
  float red[4][128];
  float cmb[128];
  float uld[128];
  float tpw[2][4][128];
};

__global__ __launch_bounds__(512, 2) void k_scores_mfma3(
    const float* __restrict__ ctx, const short* __restrict__ BtH,
    const short* __restrict__ BtL, const float* __restrict__ W,
    float* __restrict__ P, float* __restrict__ tpart) {
  __shared__ Smem3 sm;
  int p = blockIdx.x;
  int b = (p & 7) | ((p >> 5) << 3);   // 4 c-blocks of a batch -> same XCD
  int cblk = (p >> 3) & 3;
  int c0 = cblk * 128;
  int tid = threadIdx.x;
  int lane = tid & 63, wv = tid >> 6;
  int rowl = lane & 31, h = lane >> 5;

  f32x16 acc[2][4];
  #pragma unroll
  for (int r = 0; r < 2; r++)
    #pragma unroll
    for (int mtl = 0; mtl < 4; mtl++)
      #pragma unroll
      for (int j = 0; j < 16; j++) acc[r][mtl][j] = 0.f;

  auto stageB = [&](int bf, int ks) {
    #pragma unroll
    for (int rep = 0; rep < 2; rep++) {
      int mt = wv + 8 * rep;
      size_t off = (((size_t)b * 32 + ks) * 16 + mt) * 512 + (size_t)lane * 8;
      gl_lds16(BtH + off, &sm.Bf[bf][0][mt][0]);
      gl_lds16(BtL + off, &sm.Bf[bf][1][mt][0]);
    }
  };
  auto cvtA = [&](int bf, int ks, const float4& g0, const float4& g1, float& au) {
    float xs[8] = {g0.x, g0.y, g0.z, g0.w, g1.x, g1.y, g1.z, g1.w};
    int k = 16 * ks + 8 * h;
    float4 w0 = *(const float4*)&sm.sW[k];
    float4 w1 = *(const float4*)&sm.sW[k + 4];
    float ws[8] = {w0.x, w0.y, w0.z, w0.w, w1.x, w1.y, w1.z, w1.w};
    short8 vh, vl;
    #pragma unroll
    for (int e = 0; e < 8; e++) {
      unsigned short hb = bf16_rn(xs[e]);
      float hf = __uint_as_float((unsigned)hb << 16);
      vh[e] = (short)hb;
      vl[e] = (short)bf16_rn(xs[e] - hf);
      au = fmaf(xs[e], ws[e], au);
    }
    *(short8*)&sm.Af[bf][0][wv][lane] = vh;
    *(short8*)&sm.Af[bf][1][wv][lane] = vl;
  };

  sm.sW[tid] = W[tid];
  float accu = 0.f;
  stageB(0, 0);
  const float* arow = ctx + ((size_t)b * LC_ + c0 + 32 * wv + rowl) * D_ + 8 * h;
  float4 g0, g1;
  if (wv < 4) {
    g0 = *(const float4*)(arow);
    g1 = *(const float4*)(arow + 4);
  }
  __syncthreads();                      // sW visible
  if (wv < 4) cvtA(0, 0, g0, g1, accu);
  __syncthreads();                      // Af written, Bf gl_lds drained

  for (int ks = 0; ks < 32; ks++) {
    int buf = ks & 1;
    if (ks < 31) {
      stageB(buf ^ 1, ks + 1);
      if (wv < 4) {
        const float* ap = arow + 16 * (ks + 1);
        g0 = *(const float4*)ap;
        g1 = *(const float4*)(ap + 4);
      }
    }
    int rt0 = (wv >> 2) * 2;
    short8 ah0 = sm.Af[buf][0][rt0][lane];
    short8 ah1 = sm.Af[buf][0][rt0 + 1][lane];
    short8 al0 = sm.Af[buf][1][rt0][lane];
    short8 al1 = sm.Af[buf][1][rt0 + 1][lane];
    #pragma unroll
    for (int mtl = 0; mtl < 4; mtl++) {
      int mtg = (wv & 3) * 4 + mtl;
      short8 bh = sm.Bf[buf][0][mtg][lane];
      short8 bl = sm.Bf[buf][1][mtg][lane];
      acc[0][mtl] = __builtin_amdgcn_mfma_f32_32x32x16_bf16(ah0, bh, acc[0][mtl], 0, 0, 0);
      acc[0][mtl] = __builtin_amdgcn_mfma_f32_32x32x16_bf16(ah0, bl, acc[0][mtl], 0, 0, 0);
      acc[0][mtl] = __builtin_amdgcn_mfma_f32_32x32x16_bf16(al0, bh, acc[0][mtl], 0, 0, 0);
      acc[1][mtl] = __builtin_amdgcn_mfma_f32_32x32x16_bf16(ah1, bh, acc[1][mtl], 0, 0, 0);
      acc[1][mtl] = __builtin_amdgcn_mfma_f32_32x32x16_bf16(ah1, bl, acc[1][mtl], 0, 0, 0);
      acc[1][mtl] = __builtin_amdgcn_mfma_f32_32x32x16_bf16(al1, bh, acc[1][mtl], 0, 0, 0);
    }
    if (ks < 31 && wv < 4) cvtA(buf ^ 1, ks + 1, g0, g1, accu);
    __syncthreads();
  }

  // u for this block's 128 c-rows (computed by stage waves)
  if (wv < 4) {
    accu += __shfl_xor(accu, 32, 64);
    if (h == 0) sm.uld[32 * wv + rowl] = accu;
  }

  // ---- softmax over m=512 per c-row (cross-wave via LDS) ----
  #pragma unroll
  for (int r = 0; r < 2; r++)
    #pragma unroll
    for (int j = 0; j < 16; j++) {
      float mx = fmaxf(fmaxf(acc[r][0][j], acc[r][1][j]),
                       fmaxf(acc[r][2][j], acc[r][3][j]));
      #pragma unroll
      for (int s = 1; s <= 16; s <<= 1) mx = fmaxf(mx, __shfl_xor(mx, s, 64));
      if (rowl == 0)
        sm.red[wv & 3][64 * (wv >> 2) + 32 * r + (j & 3) + 8 * (j >> 2) + 4 * h] = mx;
    }
  __syncthreads();
  if (tid < 128)
    sm.cmb[tid] = fmaxf(fmaxf(sm.red[0][tid], sm.red[1][tid]),
                        fmaxf(sm.red[2][tid], sm.red[3][tid]));
  __syncthreads();
  #pragma unroll
  for (int r = 0; r < 2; r++)
    #pragma unroll
    for (int j = 0; j < 16; j++) {
      int row = 64 * (wv >> 2) + 32 * r + (j & 3) + 8 * (j >> 2) + 4 * h;
      float mx = sm.cmb[row];
      float s = 0.f;
      #pragma unroll
      for (int mtl = 0; mtl < 4; mtl++) {
        float e = __expf(acc[r][mtl][j] - mx);
        acc[r][mtl][j] = e;
        s += e;
      }
      #pragma unroll
      for (int st = 1; st <= 16; st <<= 1) s += __shfl_xor(s, st, 64);
      if (rowl == 0) sm.red[wv & 3][row] = s;
    }
  __syncthreads();
  if (tid < 128)
    sm.cmb[tid] = sm.red[0][tid] + sm.red[1][tid] + sm.red[2][tid] + sm.red[3][tid];
  __syncthreads();

  // ---- P write + fused t-partials ----
  float* Pb = P + ((size_t)b * LC_ + c0) * LM_;
  float tp[4] = {0.f, 0.f, 0.f, 0.f};
  #pragma unroll
  for (int r = 0; r < 2; r++)
    #pragma unroll
    for (int j = 0; j < 16; j++) {
      int row = 64 * (wv >> 2) + 32 * r + (j & 3) + 8 * (j >> 2) + 4 * h;
      float rinv = 1.f / sm.cmb[row];
      float uu = sm.uld[row];
      #pragma unroll
      for (int mtl = 0; mtl < 4; mtl++) {
        float pv = acc[r][mtl][j] * rinv;
        Pb[(size_t)row * LM_ + 128 * (wv & 3) + 32 * mtl + rowl] = pv;
        tp[mtl] = fmaf(pv, uu, tp[mtl]);
      }
    }
  #pragma unroll
  for (int mtl = 0; mtl < 4; mtl++) tp[mtl] += __shfl_xor(tp[mtl], 32, 64);
  if (h == 0) {
    #pragma unroll
    for (int mtl = 0; mtl < 4; mtl++)
      sm.tpw[wv >> 2][wv & 3][32 * mtl + rowl] = tp[mtl];
  }
  __syncthreads();
  {
    int m = tid;
    tpart[((size_t)b * 4 + cblk) * LM_ + m] =
        sm.tpw[0][m >> 7][m & 127] + sm.tpw[1][m >> 7][m & 127];
  }
}

// ---------------- k_tw: t = v - sum(tpart); w = softmax(t) -----------------
__global__ __launch_bounds__(256) void k_tw(const float* __restrict__ tpart,
                                            const float* __restrict__ v,
                                            float* __restrict__ w_) {
  int b = blockIdx.x;
  int tid = threadIdx.x;
  int m0 = tid * 2;
  const float* tp = tpart + (size_t)b * 4 * LM_;
  float s0 = 0.f, s1 = 0.f;
  #pragma unroll
  for (int cb = 0; cb < 4; cb++) {
    s0 += tp[cb * LM_ + m0];
    s1 += tp[cb * LM_ + m0 + 1];
  }
  float x0 = v[b * LM_ + m0] - s0;
  float x1 = v[b * LM_ + m0 + 1] - s1;
  float mx = fmaxf(x0, x1);
  #pragma unroll
  for (int s = 32; s >= 1; s >>= 1) mx = fmaxf(mx, __shfl_xor(mx, s, 64));
  __shared__ float redm[4], reds[4];
  int wvv = tid >> 6, ln = tid & 63;
  if (ln == 0) redm[wvv] = mx;
  __syncthreads();
  mx = fmaxf(fmaxf(redm[0], redm[1]), fmaxf(redm[2], redm[3]));
  float e0 = __expf(x0 - mx), e1 = __expf(x1 - mx);
  float sum = e0 + e1;
  #pragma unroll
  for (int s = 32; s >= 1; s >>= 1) sum += __shfl_xor(sum, s, 64);
  if (ln == 0) reds[wvv] = sum;
  __syncthreads();
  sum = reds[0] + reds[1] + reds[2] + reds[3];
  float rinv = 1.0f / sum;
  float2 o; o.x = e0 * rinv; o.y = e1 * rinv;
  *(float2*)&w_[b * LM_ + m0] = o;
}

// ---------------- k_q: q[b,c] = sum_m P[b,c,m]*w[b,m] ----------------------
__global__ __launch_bounds__(256) void k_q(const float* __restrict__ P,
                                           const float* __restrict__ w,
                                           float* __restrict__ q) {
  int b = blockIdx.y;
  int c0 = blockIdx.x * 32;
  int wvv = threadIdx.x >> 6, ln = threadIdx.x & 63;
  __shared__ float sw[LM_];
  *(float2*)&sw[threadIdx.x * 2] = *(const float2*)&w[b * LM_ + threadIdx.x * 2];
  __syncthreads();
  #pragma unroll
  for (int rr = 0; rr < 8; rr++) {
    int c = c0 + wvv * 8 + rr;
    const float4* Pr = (const float4*)(P + ((size_t)b * LC_ + c) * LM_) + ln * 2;
    float4 p0 = Pr[0], p1 = Pr[1];
    const float4* wr = (const float4*)sw + ln * 2;
    float4 w0 = wr[0], w1 = wr[1];
    float acc = p0.x*w0.x + p0.y*w0.y + p0.z*w0.z + p0.w*w0.w
              + p1.x*w1.x + p1.y*w1.y + p1.z*w1.z + p1.w*w1.w;
    #pragma unroll
    for (int s = 32; s >= 1; s >>= 1) acc += __shfl_xor(acc, s, 64);
    if (ln == 0) q[b * LC_ + c] = acc;
  }
}

// ---------------- k_out: out[b,d] = sum_m w*main - sum_c q*ctx -------------
__global__ __launch_bounds__(256) void k_out(const float* __restrict__ ctx,
                                             const float* __restrict__ mn,
                                             const float* __restrict__ w,
                                             const float* __restrict__ q,
                                             float* __restrict__ out) {
  int b = blockIdx.y;
  int d0 = blockIdx.x * 64;
  int td = threadIdx.x & 63;
  int tg = threadIdx.x >> 6;
  const float* Mb = mn  + (size_t)b * LM_ * D_ + d0;
  const float* Cb = ctx + (size_t)b * LC_ * D_ + d0;
  const float* wb = w + b * LM_;
  const float* qb = q + b * LC_;
  float acc = 0.f;
  #pragma unroll 4
  for (int m = tg; m < LM_; m += 4) acc += wb[m] * Mb[(size_t)m * D_ + td];
  #pragma unroll 4
  for (int c = tg; c < LC_; c += 4) acc -= qb[c] * Cb[(size_t)c * D_ + td];
  __shared__ float red[4][64];
  red[tg][td] = acc;
  __syncthreads();
  if (tg == 0)
    out[b * D_ + d0 + td] = red[0][td] + red[1][td] + red[2][td] + red[3][td];
}

// =====================  LAUNCH  ============================================
extern "C" void kernel_launch(void* const* d_in, const int* in_sizes, int n_in,
                              void* d_out, int out_size, void* d_ws, size_t ws_size,
                              hipStream_t stream) {
  const float* ctx = (const float*)d_in[0];
  const float* mn  = (const float*)d_in[1];
  const float* W   = (const float*)d_in[2];
  float* out = (float*)d_out;

  char* base = (char*)d_ws;
  size_t nPbytes = (size_t)B_ * LC_ * LM_ * 4;       // 134 MB
  size_t planeB  = (size_t)B_ * LM_ * D_ * 2;        // 67 MB per plane

  float* P   = (float*)base;
  short* BtH = (short*)(base + nPbytes);
  short* BtL = (short*)(base + nPbytes + planeB);
  char* p2 = base + nPbytes + 2 * planeB;
  float* tpart = (float*)p2;  p2 += (size_t)B_ * 4 * LM_ * 4;
  float* v = (float*)p2;      p2 += (size_t)B_ * LM_ * 4;
  float* w = (float*)p2;      p2 += (size_t)B_ * LM_ * 4;
  float* q = (float*)p2;

  k_cvt_main<<<dim3(512), 256, 0, stream>>>(mn, W, BtH, BtL, v);
  k_scores_mfma3<<<dim3(512), 512, 0, stream>>>(ctx, BtH, BtL, W, P, tpart);
  k_tw<<<dim3(B_), 256, 0, stream>>>(tpart, v, w);
  k_q<<<dim3(LC_ / 32, B_), 256, 0, stream>>>(P, w, q);
  k_out<<<dim3(D_ / 64, B_), 256, 0, stream>>>(ctx, mn, w, q, out);
}